// Round 1
// baseline (832.654 us; speedup 1.0000x reference)
//
#include <hip/hip_runtime.h>

#define NN 100000
#define EE 1600000
#define IND 512
#define HIDD 128
#define OUTD 16

// ---------------- degree count ----------------
__global__ void k_deg(const int* __restrict__ dst, int* __restrict__ deg) {
    int i = blockIdx.x * blockDim.x + threadIdx.x;
    int stride = gridDim.x * blockDim.x;
    for (; i < EE; i += stride) atomicAdd(&deg[dst[i]], 1);
}

// ---------------- norm factors ----------------
__global__ void k_norm(const int* __restrict__ deg, float* __restrict__ dis,
                       float* __restrict__ dinv) {
    int i = blockIdx.x * blockDim.x + threadIdx.x;
    if (i < NN) {
        float d = (float)(deg[i] + 1);
        dis[i] = rsqrtf(d);
        dinv[i] = 1.0f / d;
    }
}

// ---------------- scan (3 phases) ----------------
__global__ void k_scan_local(const int* __restrict__ deg, int* __restrict__ incl,
                             int* __restrict__ bsum) {
    __shared__ int s[256];
    int tid = threadIdx.x;
    int i = blockIdx.x * 256 + tid;
    int v = (i < NN) ? deg[i] : 0;
    s[tid] = v;
    __syncthreads();
    for (int off = 1; off < 256; off <<= 1) {
        int t = (tid >= off) ? s[tid - off] : 0;
        __syncthreads();
        s[tid] += t;
        __syncthreads();
    }
    if (i < NN) incl[i] = s[tid];
    if (tid == 255) bsum[blockIdx.x] = s[255];
}

__global__ void k_scan_bsum(const int* __restrict__ bsum, int* __restrict__ boff, int n) {
    __shared__ int s[512];
    int tid = threadIdx.x;
    int v = (tid < n) ? bsum[tid] : 0;
    s[tid] = v;
    __syncthreads();
    for (int off = 1; off < 512; off <<= 1) {
        int t = (tid >= off) ? s[tid - off] : 0;
        __syncthreads();
        s[tid] += t;
        __syncthreads();
    }
    if (tid < n) boff[tid] = s[tid] - v;  // exclusive
}

__global__ void k_scan_final(const int* __restrict__ incl, const int* __restrict__ deg,
                             const int* __restrict__ boff, int* __restrict__ rs,
                             int* __restrict__ cursor) {
    int i = blockIdx.x * 256 + threadIdx.x;
    if (i < NN) {
        int v = incl[i] + boff[i >> 8];  // global inclusive
        int start = v - deg[i];
        rs[i] = start;
        cursor[i] = start;
        if (i == NN - 1) rs[NN] = v;  // == EE
    }
}

// ---------------- CSR fill ----------------
__global__ void k_fill(const int* __restrict__ src, const int* __restrict__ dst,
                       int* __restrict__ cursor, int* __restrict__ csr) {
    int i = blockIdx.x * blockDim.x + threadIdx.x;
    int stride = gridDim.x * blockDim.x;
    for (; i < EE; i += stride) {
        int d = dst[i];
        int pos = atomicAdd(&cursor[d], 1);
        csr[pos] = src[i];
    }
}

// ---------------- fp32 GEMM: C[M][128] = A[M][K] @ W[K][128] ----------------
__global__ __launch_bounds__(256) void k_gemm(const float* __restrict__ A,
                                              const float* __restrict__ W,
                                              float* __restrict__ C, int M, int K) {
    __shared__ float xs[32][65];   // transposed x tile [k][m], padded
    __shared__ float ws[32][128];  // W tile [k][n]
    int tid = threadIdx.x;
    int row0 = blockIdx.x * 64;
    int tc = tid & 31;   // col group: cols tc*4 .. tc*4+3
    int tr = tid >> 5;   // row group: rows tr*8 .. tr*8+7
    float acc[8][4];
#pragma unroll
    for (int r = 0; r < 8; r++)
#pragma unroll
        for (int c = 0; c < 4; c++) acc[r][c] = 0.0f;

    for (int k0 = 0; k0 < K; k0 += 32) {
        // stage A tile: 64 rows x 32 k = 512 float4, 2 per thread
#pragma unroll
        for (int p = 0; p < 2; p++) {
            int idx = p * 256 + tid;
            int r = idx >> 3, f4 = idx & 7;
            int gr = row0 + r;
            float4 v = make_float4(0.f, 0.f, 0.f, 0.f);
            if (gr < M) v = *(const float4*)(A + (size_t)gr * K + k0 + f4 * 4);
            xs[f4 * 4 + 0][r] = v.x;
            xs[f4 * 4 + 1][r] = v.y;
            xs[f4 * 4 + 2][r] = v.z;
            xs[f4 * 4 + 3][r] = v.w;
        }
        // stage W tile: 32 k x 128 n = 1024 float4, 4 per thread
#pragma unroll
        for (int p = 0; p < 4; p++) {
            int idx = p * 256 + tid;
            int kk = idx >> 5, c4 = idx & 31;
            float4 v = *(const float4*)(W + (size_t)(k0 + kk) * 128 + c4 * 4);
            *(float4*)(&ws[kk][c4 * 4]) = v;
        }
        __syncthreads();
#pragma unroll
        for (int k = 0; k < 32; k++) {
            float4 w4 = *(const float4*)(&ws[k][tc * 4]);
            float a[8];
#pragma unroll
            for (int r = 0; r < 8; r++) a[r] = xs[k][tr * 8 + r];
#pragma unroll
            for (int r = 0; r < 8; r++) {
                acc[r][0] += a[r] * w4.x;
                acc[r][1] += a[r] * w4.y;
                acc[r][2] += a[r] * w4.z;
                acc[r][3] += a[r] * w4.w;
            }
        }
        __syncthreads();
    }
#pragma unroll
    for (int r = 0; r < 8; r++) {
        int gr = row0 + tr * 8 + r;
        if (gr < M) {
            float4 v = make_float4(acc[r][0], acc[r][1], acc[r][2], acc[r][3]);
            *(float4*)(C + (size_t)gr * 128 + tc * 4) = v;
        }
    }
}

// ---------------- aggregation: y[i] = relu(sum_{e: dst=i} dis[s]dis[i] h[s] + dinv[i] h[i] + b)
__global__ __launch_bounds__(256) void k_agg(const float* __restrict__ h,
                                             const int* __restrict__ rs,
                                             const int* __restrict__ csr,
                                             const float* __restrict__ dis,
                                             const float* __restrict__ dinv,
                                             const float* __restrict__ bias,
                                             float* __restrict__ y) {
    int node = blockIdx.x * 4 + (threadIdx.x >> 6);
    int lane = threadIdx.x & 63;
    if (node >= NN) return;
    float di = dis[node];
    float dv = dinv[node];
    float acc0 = h[(size_t)node * 128 + lane] * dv;
    float acc1 = h[(size_t)node * 128 + 64 + lane] * dv;
    int e0 = rs[node], e1 = rs[node + 1];
    for (int e = e0; e < e1; ++e) {
        int s = csr[e];
        float w = di * dis[s];
        acc0 += w * h[(size_t)s * 128 + lane];
        acc1 += w * h[(size_t)s * 128 + 64 + lane];
    }
    acc0 += bias[lane];
    acc1 += bias[64 + lane];
    acc0 = fmaxf(acc0, 0.0f);
    acc1 = fmaxf(acc1, 0.0f);
    y[(size_t)node * 128 + lane] = acc0;
    y[(size_t)node * 128 + 64 + lane] = acc1;
}

// ---------------- head: out[N][16] = emb[N][128] @ Wl[128][16] + bl ----------------
__global__ __launch_bounds__(256) void k_out(const float* __restrict__ emb,
                                             const float* __restrict__ Wl,
                                             const float* __restrict__ bl,
                                             float* __restrict__ out) {
    __shared__ float wl_s[128 * 16];
    __shared__ float es[16][129];
    int tid = threadIdx.x;
    int row0 = blockIdx.x * 16;
#pragma unroll
    for (int p = 0; p < 8; p++) wl_s[p * 256 + tid] = Wl[p * 256 + tid];
#pragma unroll
    for (int p = 0; p < 8; p++) {
        int idx = p * 256 + tid;
        int r = idx >> 7, c = idx & 127;
        int gr = row0 + r;
        es[r][c] = (gr < NN) ? emb[(size_t)gr * 128 + c] : 0.0f;
    }
    __syncthreads();
    int r = tid >> 4, o = tid & 15;
    float acc = bl[o];
#pragma unroll
    for (int k = 0; k < 128; k++) acc += es[r][k] * wl_s[k * 16 + o];
    int gr = row0 + r;
    if (gr < NN) out[(size_t)gr * 16 + o] = acc;
}

extern "C" void kernel_launch(void* const* d_in, const int* in_sizes, int n_in,
                              void* d_out, int out_size, void* d_ws, size_t ws_size,
                              hipStream_t stream) {
    const float* x  = (const float*)d_in[0];
    const int* ei   = (const int*)d_in[1];  // [2][E]: row0=src, row1=dst
    const float* W1 = (const float*)d_in[2];
    const float* b1 = (const float*)d_in[3];
    const float* W2 = (const float*)d_in[4];
    const float* b2 = (const float*)d_in[5];
    const float* Wl = (const float*)d_in[6];
    const float* bl = (const float*)d_in[7];
    const int* src = ei;
    const int* dst = ei + EE;

    float* outp = (float*)d_out;              // [N][16]
    float* emb  = outp + (size_t)NN * OUTD;   // [N][128]

    // workspace layout
    float* h_a = (float*)d_ws;                 // N*128
    float* h_b = h_a + (size_t)NN * 128;       // N*128
    int* deg   = (int*)(h_b + (size_t)NN * 128);
    float* dis = (float*)(deg + NN);
    float* dinv = dis + NN;
    int* incl  = (int*)(dinv + NN);
    int* rs    = incl + NN;                    // N+1
    int* cursor = rs + NN + 8;
    int* bsum  = cursor + NN;                  // 391
    int* boff  = bsum + 512;
    int* csr   = boff + 512;                   // E

    const int NB_N = (NN + 255) / 256;  // 391

    hipMemsetAsync(deg, 0, (size_t)NN * sizeof(int), stream);
    k_deg<<<2048, 256, 0, stream>>>(dst, deg);
    k_norm<<<NB_N, 256, 0, stream>>>(deg, dis, dinv);
    k_scan_local<<<NB_N, 256, 0, stream>>>(deg, incl, bsum);
    k_scan_bsum<<<1, 512, 0, stream>>>(bsum, boff, NB_N);
    k_scan_final<<<NB_N, 256, 0, stream>>>(incl, deg, boff, rs, cursor);
    k_fill<<<2048, 256, 0, stream>>>(src, dst, cursor, csr);

    // layer 1: h_a = x @ W1 ; h_b = relu(agg(h_a) + b1)
    k_gemm<<<(NN + 63) / 64, 256, 0, stream>>>(x, W1, h_a, NN, IND);
    k_agg<<<(NN + 3) / 4, 256, 0, stream>>>(h_a, rs, csr, dis, dinv, b1, h_b);
    // layer 2: h_a = h_b @ W2 ; emb = relu(agg(h_a) + b2)
    k_gemm<<<(NN + 63) / 64, 256, 0, stream>>>(h_b, W2, h_a, NN, HIDD);
    k_agg<<<(NN + 3) / 4, 256, 0, stream>>>(h_a, rs, csr, dis, dinv, b2, emb);
    // head
    k_out<<<(NN + 15) / 16, 256, 0, stream>>>(emb, Wl, bl, outp);
}

// Round 2
// 589.612 us; speedup vs baseline: 1.4122x; 1.4122x over previous
//
#include <hip/hip_runtime.h>

#define NN 100000
#define EE 1600000
#define IND 512
#define HIDD 128
#define OUTD 16

typedef __bf16 bf16x8 __attribute__((ext_vector_type(8)));
typedef float f32x4 __attribute__((ext_vector_type(4)));

__device__ __forceinline__ ushort f2bf(float f) {
    union { float f; uint u; } v; v.f = f;
    uint r = v.u + 0x7FFFu + ((v.u >> 16) & 1u);
    return (ushort)(r >> 16);
}

// ---------------- degree count ----------------
__global__ void k_deg(const int* __restrict__ dst, int* __restrict__ deg) {
    int i = blockIdx.x * blockDim.x + threadIdx.x;
    int stride = gridDim.x * blockDim.x;
    for (; i < EE; i += stride) atomicAdd(&deg[dst[i]], 1);
}

// ---------------- norm factors ----------------
__global__ void k_norm(const int* __restrict__ deg, float* __restrict__ dis,
                       float* __restrict__ dinv) {
    int i = blockIdx.x * blockDim.x + threadIdx.x;
    if (i < NN) {
        float d = (float)(deg[i] + 1);
        dis[i] = rsqrtf(d);
        dinv[i] = 1.0f / d;
    }
}

// ---------------- scan (3 phases) ----------------
__global__ void k_scan_local(const int* __restrict__ deg, int* __restrict__ incl,
                             int* __restrict__ bsum) {
    __shared__ int s[256];
    int tid = threadIdx.x;
    int i = blockIdx.x * 256 + tid;
    int v = (i < NN) ? deg[i] : 0;
    s[tid] = v;
    __syncthreads();
    for (int off = 1; off < 256; off <<= 1) {
        int t = (tid >= off) ? s[tid - off] : 0;
        __syncthreads();
        s[tid] += t;
        __syncthreads();
    }
    if (i < NN) incl[i] = s[tid];
    if (tid == 255) bsum[blockIdx.x] = s[255];
}

__global__ void k_scan_bsum(const int* __restrict__ bsum, int* __restrict__ boff, int n) {
    __shared__ int s[512];
    int tid = threadIdx.x;
    int v = (tid < n) ? bsum[tid] : 0;
    s[tid] = v;
    __syncthreads();
    for (int off = 1; off < 512; off <<= 1) {
        int t = (tid >= off) ? s[tid - off] : 0;
        __syncthreads();
        s[tid] += t;
        __syncthreads();
    }
    if (tid < n) boff[tid] = s[tid] - v;  // exclusive
}

__global__ void k_scan_final(const int* __restrict__ incl, const int* __restrict__ deg,
                             const int* __restrict__ boff, int* __restrict__ rs,
                             int* __restrict__ cursor) {
    int i = blockIdx.x * 256 + threadIdx.x;
    if (i < NN) {
        int v = incl[i] + boff[i >> 8];  // global inclusive
        int start = v - deg[i];
        rs[i] = start;
        cursor[i] = start;
        if (i == NN - 1) rs[NN] = v;  // == EE
    }
}

// ---------------- CSR fill: (src, weight) pairs ----------------
__global__ void k_fill(const int* __restrict__ src, const int* __restrict__ dst,
                       const float* __restrict__ dis, int* __restrict__ cursor,
                       int2* __restrict__ ew) {
    int i = blockIdx.x * blockDim.x + threadIdx.x;
    int stride = gridDim.x * blockDim.x;
    for (; i < EE; i += stride) {
        int d = dst[i];
        int s = src[i];
        int pos = atomicAdd(&cursor[d], 1);
        ew[pos] = make_int2(s, __float_as_int(dis[s] * dis[d]));
    }
}

// ---------------- W prep: fp32 [K][128] -> bf16 transposed [128][K] ----------------
__global__ void k_prep_w(const float* __restrict__ W, ushort* __restrict__ Wt, int K) {
    int i = blockIdx.x * 256 + threadIdx.x;
    if (i < K * 128) {
        int k = i >> 7, n = i & 127;
        Wt[n * K + k] = f2bf(W[i]);
    }
}

// ---------------- bf16 MFMA GEMM: C[M][128] = A[M][K] @ W[K][128] ----------------
// Wt: [128][K] bf16 (pre-transposed). Output C: bf16 [M][128].
// Swapped-operand: D = Wt_frag * x_frag -> D[i=n][j=m]; lane's 4 C regs are
// consecutive n at fixed m -> packed 8B store.
template <int K, bool AFP32>
__global__ __launch_bounds__(256) void k_gemm_mfma(const void* __restrict__ Ap,
                                                   const ushort* __restrict__ Wt,
                                                   ushort* __restrict__ C, int M) {
    __shared__ ushort As[64][40];   // [m][k], padded to 80B rows (bank-rotating)
    __shared__ ushort Ws[128][40];  // [n][k]
    int tid = threadIdx.x;
    int row0 = blockIdx.x * 64;
    int wid = tid >> 6, lane = tid & 63;
    int wm = (wid & 1) * 32, wn = (wid >> 1) * 64;
    int lm = lane & 15, lk8 = (lane >> 4) * 8;

    f32x4 acc[4][2];
#pragma unroll
    for (int q = 0; q < 4; q++)
#pragma unroll
        for (int r = 0; r < 2; r++) acc[q][r] = (f32x4){0.f, 0.f, 0.f, 0.f};

    int arow = tid >> 2, akg = tid & 3;
    int gr = row0 + arow;

    for (int k0 = 0; k0 < K; k0 += 32) {
        // stage A tile (64 m x 32 k)
        if (AFP32) {
            const float* A = (const float*)Ap;
            float4 v0 = make_float4(0.f, 0.f, 0.f, 0.f), v1 = v0;
            if (gr < M) {
                const float* p = A + (size_t)gr * K + k0 + akg * 8;
                v0 = *(const float4*)(p);
                v1 = *(const float4*)(p + 4);
            }
            uint4 pk;
            pk.x = (uint)f2bf(v0.x) | ((uint)f2bf(v0.y) << 16);
            pk.y = (uint)f2bf(v0.z) | ((uint)f2bf(v0.w) << 16);
            pk.z = (uint)f2bf(v1.x) | ((uint)f2bf(v1.y) << 16);
            pk.w = (uint)f2bf(v1.z) | ((uint)f2bf(v1.w) << 16);
            *(uint4*)&As[arow][akg * 8] = pk;
        } else {
            const ushort* A = (const ushort*)Ap;
            uint4 v = make_uint4(0, 0, 0, 0);
            if (gr < M) v = *(const uint4*)(A + (size_t)gr * K + k0 + akg * 8);
            *(uint4*)&As[arow][akg * 8] = v;
        }
        // stage W tile (128 n x 32 k)
#pragma unroll
        for (int p = 0; p < 2; p++) {
            int idx = p * 256 + tid;
            int n = idx >> 2, kg = idx & 3;
            uint4 v = *(const uint4*)(Wt + (size_t)n * K + k0 + kg * 8);
            *(uint4*)&Ws[n][kg * 8] = v;
        }
        __syncthreads();

        bf16x8 xf[2], wf[4];
#pragma unroll
        for (int r = 0; r < 2; r++) xf[r] = *(const bf16x8*)&As[wm + r * 16 + lm][lk8];
#pragma unroll
        for (int q = 0; q < 4; q++) wf[q] = *(const bf16x8*)&Ws[wn + q * 16 + lm][lk8];
#pragma unroll
        for (int q = 0; q < 4; q++)
#pragma unroll
            for (int r = 0; r < 2; r++)
                acc[q][r] = __builtin_amdgcn_mfma_f32_16x16x32_bf16(wf[q], xf[r], acc[q][r], 0, 0, 0);
        __syncthreads();
    }

    // C write: m = row0+wm+r*16+(lane&15), n = wn+q*16+(lane>>4)*4 + reg
    int cn4 = (lane >> 4) * 4;
#pragma unroll
    for (int r = 0; r < 2; r++) {
        int m = row0 + wm + r * 16 + lm;
        if (m < M) {
#pragma unroll
            for (int q = 0; q < 4; q++) {
                int n = wn + q * 16 + cn4;
                uint2 o;
                o.x = (uint)f2bf(acc[q][r][0]) | ((uint)f2bf(acc[q][r][1]) << 16);
                o.y = (uint)f2bf(acc[q][r][2]) | ((uint)f2bf(acc[q][r][3]) << 16);
                *(uint2*)(C + (size_t)m * 128 + n) = o;
            }
        }
    }
}

// ---------------- aggregation over bf16 h ----------------
// y[i] = relu(sum_e w_e * h[src_e] + dinv[i]*h[i] + b); h bf16, acc fp32.
template <bool OUTF32>
__global__ __launch_bounds__(256) void k_agg_bf(const ushort* __restrict__ h,
                                                const int* __restrict__ rs,
                                                const int2* __restrict__ ew,
                                                const float* __restrict__ dinv,
                                                const float* __restrict__ bias,
                                                void* __restrict__ yv) {
    int node = blockIdx.x * 4 + (threadIdx.x >> 6);
    int lane = threadIdx.x & 63;
    if (node >= NN) return;
    float dv = dinv[node];
    uint sv = *(const uint*)(h + (size_t)node * 128 + lane * 2);
    float acc0 = __uint_as_float(sv << 16) * dv;
    float acc1 = __uint_as_float(sv & 0xffff0000u) * dv;
    int e0 = rs[node], e1 = rs[node + 1];
    for (int e = e0; e < e1; ++e) {
        int2 p = ew[e];
        float w = __int_as_float(p.y);
        uint hv = *(const uint*)(h + (size_t)p.x * 128 + lane * 2);
        acc0 += w * __uint_as_float(hv << 16);
        acc1 += w * __uint_as_float(hv & 0xffff0000u);
    }
    acc0 = fmaxf(acc0 + bias[lane * 2], 0.0f);
    acc1 = fmaxf(acc1 + bias[lane * 2 + 1], 0.0f);
    if (OUTF32) {
        float2* y = (float2*)yv;
        y[(size_t)node * 64 + lane] = make_float2(acc0, acc1);
    } else {
        uint* y = (uint*)yv;
        y[(size_t)node * 64 + lane] = (uint)f2bf(acc0) | ((uint)f2bf(acc1) << 16);
    }
}

// ---------------- head: out[N][16] = emb[N][128] @ Wl[128][16] + bl ----------------
__global__ __launch_bounds__(256) void k_out(const float* __restrict__ emb,
                                             const float* __restrict__ Wl,
                                             const float* __restrict__ bl,
                                             float* __restrict__ out) {
    __shared__ float wl_s[128 * 16];
    __shared__ float es[16][129];
    int tid = threadIdx.x;
    int row0 = blockIdx.x * 16;
#pragma unroll
    for (int p = 0; p < 8; p++) wl_s[p * 256 + tid] = Wl[p * 256 + tid];
#pragma unroll
    for (int p = 0; p < 8; p++) {
        int idx = p * 256 + tid;
        int r = idx >> 7, c = idx & 127;
        int gr = row0 + r;
        es[r][c] = (gr < NN) ? emb[(size_t)gr * 128 + c] : 0.0f;
    }
    __syncthreads();
    int r = tid >> 4, o = tid & 15;
    float acc = bl[o];
#pragma unroll
    for (int k = 0; k < 128; k++) acc += es[r][k] * wl_s[k * 16 + o];
    int gr = row0 + r;
    if (gr < NN) out[(size_t)gr * 16 + o] = acc;
}

extern "C" void kernel_launch(void* const* d_in, const int* in_sizes, int n_in,
                              void* d_out, int out_size, void* d_ws, size_t ws_size,
                              hipStream_t stream) {
    const float* x  = (const float*)d_in[0];
    const int* ei   = (const int*)d_in[1];  // [2][E]: row0=src, row1=dst
    const float* W1 = (const float*)d_in[2];
    const float* b1 = (const float*)d_in[3];
    const float* W2 = (const float*)d_in[4];
    const float* b2 = (const float*)d_in[5];
    const float* Wl = (const float*)d_in[6];
    const float* bl = (const float*)d_in[7];
    const int* src = ei;
    const int* dst = ei + EE;

    float* outp = (float*)d_out;             // [N][16]
    float* emb  = outp + (size_t)NN * OUTD;  // [N][128] fp32

    // workspace layout (16B-aligned chunks)
    int2* ew    = (int2*)d_ws;                        // E pairs (src, w)
    ushort* h_a = (ushort*)(ew + EE);                 // N*128 bf16
    ushort* h_b = h_a + (size_t)NN * 128;             // N*128 bf16
    ushort* Wt1 = h_b + (size_t)NN * 128;             // 128*512 bf16
    ushort* Wt2 = Wt1 + 128 * 512;                    // 128*128 bf16
    int* deg    = (int*)(Wt2 + 128 * 128);
    float* dis  = (float*)(deg + NN);
    float* dinv = dis + NN;
    int* incl   = (int*)(dinv + NN);
    int* rs     = incl + NN;                          // N+1
    int* cursor = rs + NN + 8;
    int* bsum   = cursor + NN;
    int* boff   = bsum + 512;

    const int NB_N = (NN + 255) / 256;  // 391

    hipMemsetAsync(deg, 0, (size_t)NN * sizeof(int), stream);
    k_deg<<<2048, 256, 0, stream>>>(dst, deg);
    k_norm<<<NB_N, 256, 0, stream>>>(deg, dis, dinv);
    k_scan_local<<<NB_N, 256, 0, stream>>>(deg, incl, bsum);
    k_scan_bsum<<<1, 512, 0, stream>>>(bsum, boff, NB_N);
    k_scan_final<<<NB_N, 256, 0, stream>>>(incl, deg, boff, rs, cursor);
    k_fill<<<2048, 256, 0, stream>>>(src, dst, dis, cursor, ew);

    k_prep_w<<<(512 * 128 + 255) / 256, 256, 0, stream>>>(W1, Wt1, 512);
    k_prep_w<<<(128 * 128 + 255) / 256, 256, 0, stream>>>(W2, Wt2, 128);

    // layer 1: h_a = bf16(x @ W1); h_b = bf16(relu(agg(h_a) + b1))
    k_gemm_mfma<IND, true><<<(NN + 63) / 64, 256, 0, stream>>>(x, Wt1, h_a, NN);
    k_agg_bf<false><<<(NN + 3) / 4, 256, 0, stream>>>(h_a, rs, ew, dinv, b1, h_b);
    // layer 2: h_a = bf16(h_b @ W2); emb = fp32(relu(agg(h_a) + b2))
    k_gemm_mfma<HIDD, false><<<(NN + 63) / 64, 256, 0, stream>>>(h_b, Wt2, h_a, NN);
    k_agg_bf<true><<<(NN + 3) / 4, 256, 0, stream>>>(h_a, rs, ew, dinv, b2, emb);
    // head
    k_out<<<(NN + 15) / 16, 256, 0, stream>>>(emb, Wl, bl, outp);
}

// Round 3
// 420.141 us; speedup vs baseline: 1.9818x; 1.4034x over previous
//
#include <hip/hip_runtime.h>

#define NN 100000
#define EE 1600000
#define IND 512
#define HIDD 128
#define OUTD 16

typedef __bf16 bf16x8 __attribute__((ext_vector_type(8)));
typedef float f32x4 __attribute__((ext_vector_type(4)));

__device__ __forceinline__ ushort f2bf(float f) {
    union { float f; uint u; } v; v.f = f;
    uint r = v.u + 0x7FFFu + ((v.u >> 16) & 1u);
    return (ushort)(r >> 16);
}

// ---------------- degree count ----------------
__global__ void k_deg(const int* __restrict__ dst, int* __restrict__ deg) {
    int i = blockIdx.x * blockDim.x + threadIdx.x;
    int stride = gridDim.x * blockDim.x;
    for (; i < EE; i += stride) atomicAdd(&deg[dst[i]], 1);
}

// ---------------- norm factors ----------------
__global__ void k_norm(const int* __restrict__ deg, float* __restrict__ dis,
                       float* __restrict__ dinv) {
    int i = blockIdx.x * blockDim.x + threadIdx.x;
    if (i < NN) {
        float d = (float)(deg[i] + 1);
        dis[i] = rsqrtf(d);
        dinv[i] = 1.0f / d;
    }
}

// ---------------- scan (3 phases) ----------------
__global__ void k_scan_local(const int* __restrict__ deg, int* __restrict__ incl,
                             int* __restrict__ bsum) {
    __shared__ int s[256];
    int tid = threadIdx.x;
    int i = blockIdx.x * 256 + tid;
    int v = (i < NN) ? deg[i] : 0;
    s[tid] = v;
    __syncthreads();
    for (int off = 1; off < 256; off <<= 1) {
        int t = (tid >= off) ? s[tid - off] : 0;
        __syncthreads();
        s[tid] += t;
        __syncthreads();
    }
    if (i < NN) incl[i] = s[tid];
    if (tid == 255) bsum[blockIdx.x] = s[255];
}

__global__ void k_scan_bsum(const int* __restrict__ bsum, int* __restrict__ boff, int n) {
    __shared__ int s[512];
    int tid = threadIdx.x;
    int v = (tid < n) ? bsum[tid] : 0;
    s[tid] = v;
    __syncthreads();
    for (int off = 1; off < 512; off <<= 1) {
        int t = (tid >= off) ? s[tid - off] : 0;
        __syncthreads();
        s[tid] += t;
        __syncthreads();
    }
    if (tid < n) boff[tid] = s[tid] - v;  // exclusive
}

__global__ void k_scan_final(const int* __restrict__ incl, const int* __restrict__ deg,
                             const int* __restrict__ boff, int* __restrict__ rs,
                             int* __restrict__ cursor) {
    int i = blockIdx.x * 256 + threadIdx.x;
    if (i < NN) {
        int v = incl[i] + boff[i >> 8];  // global inclusive
        int start = v - deg[i];
        rs[i] = start;
        cursor[i] = start;
        if (i == NN - 1) rs[NN] = v;  // == EE
    }
}

// ---------------- CSR fill: (src, weight) pairs ----------------
__global__ void k_fill(const int* __restrict__ src, const int* __restrict__ dst,
                       const float* __restrict__ dis, int* __restrict__ cursor,
                       int2* __restrict__ ew) {
    int i = blockIdx.x * blockDim.x + threadIdx.x;
    int stride = gridDim.x * blockDim.x;
    for (; i < EE; i += stride) {
        int d = dst[i];
        int s = src[i];
        int pos = atomicAdd(&cursor[d], 1);
        ew[pos] = make_int2(s, __float_as_int(dis[s] * dis[d]));
    }
}

// ---------------- W prep: fp32 [K][128] -> bf16 transposed [128][K] ----------------
__global__ void k_prep_w(const float* __restrict__ W, ushort* __restrict__ Wt, int K) {
    int i = blockIdx.x * 256 + threadIdx.x;
    if (i < K * 128) {
        int k = i >> 7, n = i & 127;
        Wt[n * K + k] = f2bf(W[i]);
    }
}

// ---------------- bf16 MFMA GEMM: C[M][128] = A[M][K] @ W[K][128] ----------------
template <int K, bool AFP32>
__global__ __launch_bounds__(256) void k_gemm_mfma(const void* __restrict__ Ap,
                                                   const ushort* __restrict__ Wt,
                                                   ushort* __restrict__ C, int M) {
    __shared__ ushort As[64][40];   // [m][k], padded
    __shared__ ushort Ws[128][40];  // [n][k]
    int tid = threadIdx.x;
    int row0 = blockIdx.x * 64;
    int wid = tid >> 6, lane = tid & 63;
    int wm = (wid & 1) * 32, wn = (wid >> 1) * 64;
    int lm = lane & 15, lk8 = (lane >> 4) * 8;

    f32x4 acc[4][2];
#pragma unroll
    for (int q = 0; q < 4; q++)
#pragma unroll
        for (int r = 0; r < 2; r++) acc[q][r] = (f32x4){0.f, 0.f, 0.f, 0.f};

    int arow = tid >> 2, akg = tid & 3;
    int gr = row0 + arow;

    for (int k0 = 0; k0 < K; k0 += 32) {
        if (AFP32) {
            const float* A = (const float*)Ap;
            float4 v0 = make_float4(0.f, 0.f, 0.f, 0.f), v1 = v0;
            if (gr < M) {
                const float* p = A + (size_t)gr * K + k0 + akg * 8;
                v0 = *(const float4*)(p);
                v1 = *(const float4*)(p + 4);
            }
            uint4 pk;
            pk.x = (uint)f2bf(v0.x) | ((uint)f2bf(v0.y) << 16);
            pk.y = (uint)f2bf(v0.z) | ((uint)f2bf(v0.w) << 16);
            pk.z = (uint)f2bf(v1.x) | ((uint)f2bf(v1.y) << 16);
            pk.w = (uint)f2bf(v1.z) | ((uint)f2bf(v1.w) << 16);
            *(uint4*)&As[arow][akg * 8] = pk;
        } else {
            const ushort* A = (const ushort*)Ap;
            uint4 v = make_uint4(0, 0, 0, 0);
            if (gr < M) v = *(const uint4*)(A + (size_t)gr * K + k0 + akg * 8);
            *(uint4*)&As[arow][akg * 8] = v;
        }
#pragma unroll
        for (int p = 0; p < 2; p++) {
            int idx = p * 256 + tid;
            int n = idx >> 2, kg = idx & 3;
            uint4 v = *(const uint4*)(Wt + (size_t)n * K + k0 + kg * 8);
            *(uint4*)&Ws[n][kg * 8] = v;
        }
        __syncthreads();

        bf16x8 xf[2], wf[4];
#pragma unroll
        for (int r = 0; r < 2; r++) xf[r] = *(const bf16x8*)&As[wm + r * 16 + lm][lk8];
#pragma unroll
        for (int q = 0; q < 4; q++) wf[q] = *(const bf16x8*)&Ws[wn + q * 16 + lm][lk8];
#pragma unroll
        for (int q = 0; q < 4; q++)
#pragma unroll
            for (int r = 0; r < 2; r++)
                acc[q][r] = __builtin_amdgcn_mfma_f32_16x16x32_bf16(wf[q], xf[r], acc[q][r], 0, 0, 0);
        __syncthreads();
    }

    int cn4 = (lane >> 4) * 4;
#pragma unroll
    for (int r = 0; r < 2; r++) {
        int m = row0 + wm + r * 16 + lm;
        if (m < M) {
#pragma unroll
            for (int q = 0; q < 4; q++) {
                int n = wn + q * 16 + cn4;
                uint2 o;
                o.x = (uint)f2bf(acc[q][r][0]) | ((uint)f2bf(acc[q][r][1]) << 16);
                o.y = (uint)f2bf(acc[q][r][2]) | ((uint)f2bf(acc[q][r][3]) << 16);
                *(uint2*)(C + (size_t)m * 128 + n) = o;
            }
        }
    }
}

// ---------------- aggregation over bf16 h (8-deep MLP unroll) ----------------
template <bool OUTF32>
__global__ __launch_bounds__(256) void k_agg_bf(const ushort* __restrict__ h,
                                                const int* __restrict__ rs,
                                                const int2* __restrict__ ew,
                                                const float* __restrict__ dinv,
                                                const float* __restrict__ bias,
                                                void* __restrict__ yv) {
    int node = blockIdx.x * 4 + (threadIdx.x >> 6);
    int lane = threadIdx.x & 63;
    if (node >= NN) return;
    const uint* h32 = (const uint*)h;
    float dv = dinv[node];
    uint sv = h32[(size_t)node * 64 + lane];
    float acc0 = __uint_as_float(sv << 16) * dv;
    float acc1 = __uint_as_float(sv & 0xffff0000u) * dv;
    int e = rs[node], e1 = rs[node + 1];

#define EDGE_LOAD(i) int2 p##i = ew[e + i]; uint g##i = h32[(size_t)p##i.x * 64 + lane];
#define EDGE_ACC(i) { float w##i = __int_as_float(p##i.y); \
    acc0 += w##i * __uint_as_float(g##i << 16); \
    acc1 += w##i * __uint_as_float(g##i & 0xffff0000u); }

    for (; e + 8 <= e1; e += 8) {
        EDGE_LOAD(0) EDGE_LOAD(1) EDGE_LOAD(2) EDGE_LOAD(3)
        EDGE_LOAD(4) EDGE_LOAD(5) EDGE_LOAD(6) EDGE_LOAD(7)
        EDGE_ACC(0) EDGE_ACC(1) EDGE_ACC(2) EDGE_ACC(3)
        EDGE_ACC(4) EDGE_ACC(5) EDGE_ACC(6) EDGE_ACC(7)
    }
    for (; e + 2 <= e1; e += 2) {
        EDGE_LOAD(0) EDGE_LOAD(1)
        EDGE_ACC(0) EDGE_ACC(1)
    }
    if (e < e1) {
        EDGE_LOAD(0)
        EDGE_ACC(0)
    }
#undef EDGE_LOAD
#undef EDGE_ACC

    acc0 = fmaxf(acc0 + bias[lane * 2], 0.0f);
    acc1 = fmaxf(acc1 + bias[lane * 2 + 1], 0.0f);
    if (OUTF32) {
        float2* y = (float2*)yv;
        y[(size_t)node * 64 + lane] = make_float2(acc0, acc1);
    } else {
        uint* y = (uint*)yv;
        y[(size_t)node * 64 + lane] = (uint)f2bf(acc0) | ((uint)f2bf(acc1) << 16);
    }
}

// ---------------- head: out[N][16] = emb[N][128] @ Wl[128][16] + bl ----------------
__global__ __launch_bounds__(256) void k_out(const float* __restrict__ emb,
                                             const float* __restrict__ Wl,
                                             const float* __restrict__ bl,
                                             float* __restrict__ out) {
    __shared__ float wl_s[128 * 16];
    __shared__ float es[16][129];
    int tid = threadIdx.x;
    int row0 = blockIdx.x * 16;
#pragma unroll
    for (int p = 0; p < 8; p++) wl_s[p * 256 + tid] = Wl[p * 256 + tid];
#pragma unroll
    for (int p = 0; p < 8; p++) {
        int idx = p * 256 + tid;
        int r = idx >> 7, c = idx & 127;
        int gr = row0 + r;
        es[r][c] = (gr < NN) ? emb[(size_t)gr * 128 + c] : 0.0f;
    }
    __syncthreads();
    int r = tid >> 4, o = tid & 15;
    float acc = bl[o];
#pragma unroll
    for (int k = 0; k < 128; k++) acc += es[r][k] * wl_s[k * 16 + o];
    int gr = row0 + r;
    if (gr < NN) out[(size_t)gr * 16 + o] = acc;
}

extern "C" void kernel_launch(void* const* d_in, const int* in_sizes, int n_in,
                              void* d_out, int out_size, void* d_ws, size_t ws_size,
                              hipStream_t stream) {
    const float* x  = (const float*)d_in[0];
    const int* ei   = (const int*)d_in[1];  // [2][E]: row0=src, row1=dst
    const float* W1 = (const float*)d_in[2];
    const float* b1 = (const float*)d_in[3];
    const float* W2 = (const float*)d_in[4];
    const float* b2 = (const float*)d_in[5];
    const float* Wl = (const float*)d_in[6];
    const float* bl = (const float*)d_in[7];
    const int* src = ei;
    const int* dst = ei + EE;

    float* outp = (float*)d_out;             // [N][16]
    float* emb  = outp + (size_t)NN * OUTD;  // [N][128] fp32

    int2* ew    = (int2*)d_ws;                        // E pairs (src, w)
    ushort* h_a = (ushort*)(ew + EE);                 // N*128 bf16
    ushort* h_b = h_a + (size_t)NN * 128;             // N*128 bf16
    ushort* Wt1 = h_b + (size_t)NN * 128;             // 128*512 bf16
    ushort* Wt2 = Wt1 + 128 * 512;                    // 128*128 bf16
    int* deg    = (int*)(Wt2 + 128 * 128);
    float* dis  = (float*)(deg + NN);
    float* dinv = dis + NN;
    int* incl   = (int*)(dinv + NN);
    int* rs     = incl + NN;                          // N+1
    int* cursor = rs + NN + 8;
    int* bsum   = cursor + NN;
    int* boff   = bsum + 512;

    const int NB_N = (NN + 255) / 256;  // 391

    hipMemsetAsync(deg, 0, (size_t)NN * sizeof(int), stream);
    k_deg<<<2048, 256, 0, stream>>>(dst, deg);
    k_norm<<<NB_N, 256, 0, stream>>>(deg, dis, dinv);
    k_scan_local<<<NB_N, 256, 0, stream>>>(deg, incl, bsum);
    k_scan_bsum<<<1, 512, 0, stream>>>(bsum, boff, NB_N);
    k_scan_final<<<NB_N, 256, 0, stream>>>(incl, deg, boff, rs, cursor);
    k_fill<<<2048, 256, 0, stream>>>(src, dst, dis, cursor, ew);

    k_prep_w<<<(512 * 128 + 255) / 256, 256, 0, stream>>>(W1, Wt1, 512);
    k_prep_w<<<(128 * 128 + 255) / 256, 256, 0, stream>>>(W2, Wt2, 128);

    // layer 1: h_a = bf16(x @ W1); h_b = bf16(relu(agg(h_a) + b1))
    k_gemm_mfma<IND, true><<<(NN + 63) / 64, 256, 0, stream>>>(x, Wt1, h_a, NN);
    k_agg_bf<false><<<(NN + 3) / 4, 256, 0, stream>>>(h_a, rs, ew, dinv, b1, h_b);
    // layer 2: h_a = bf16(h_b @ W2); emb = fp32(relu(agg(h_a) + b2))
    k_gemm_mfma<HIDD, false><<<(NN + 63) / 64, 256, 0, stream>>>(h_b, Wt2, h_a, NN);
    k_agg_bf<true><<<(NN + 3) / 4, 256, 0, stream>>>(h_a, rs, ew, dinv, b2, emb);
    // head
    k_out<<<(NN + 15) / 16, 256, 0, stream>>>(emb, Wl, bl, outp);
}

// Round 4
// 392.037 us; speedup vs baseline: 2.1239x; 1.0717x over previous
//
#include <hip/hip_runtime.h>

#define NN 100000
#define EE 1600000
#define IND 512
#define HIDD 128
#define OUTD 16
#define DEG_BLKS 128
#define GEMM_BLKS 1563  // ceil(NN/64)

typedef __bf16 bf16x8 __attribute__((ext_vector_type(8)));
typedef float f32x4 __attribute__((ext_vector_type(4)));

__device__ __forceinline__ ushort f2bf(float f) {
    union { float f; uint u; } v; v.f = f;
    uint r = v.u + 0x7FFFu + ((v.u >> 16) & 1u);
    return (ushort)(r >> 16);
}

// ---------------- W prep: both layers in one launch ----------------
__global__ void k_prep(const float* __restrict__ W1, const float* __restrict__ W2,
                       ushort* __restrict__ Wt1, ushort* __restrict__ Wt2) {
    int b = blockIdx.x, tid = threadIdx.x;
    if (b < 256) {  // W1: 512x128 -> Wt1[128][512]
        int i = b * 256 + tid;
        int k = i >> 7, n = i & 127;
        Wt1[n * 512 + k] = f2bf(W1[i]);
    } else {        // W2: 128x128 -> Wt2[128][128]
        int i = (b - 256) * 256 + tid;
        int k = i >> 7, n = i & 127;
        Wt2[n * 128 + k] = f2bf(W2[i]);
    }
}

// ---------------- scan (3 phases; norm fused into final) ----------------
__global__ void k_scan_local(const int* __restrict__ deg, int* __restrict__ incl,
                             int* __restrict__ bsum) {
    __shared__ int s[256];
    int tid = threadIdx.x;
    int i = blockIdx.x * 256 + tid;
    int v = (i < NN) ? deg[i] : 0;
    s[tid] = v;
    __syncthreads();
    for (int off = 1; off < 256; off <<= 1) {
        int t = (tid >= off) ? s[tid - off] : 0;
        __syncthreads();
        s[tid] += t;
        __syncthreads();
    }
    if (i < NN) incl[i] = s[tid];
    if (tid == 255) bsum[blockIdx.x] = s[255];
}

__global__ void k_scan_bsum(const int* __restrict__ bsum, int* __restrict__ boff, int n) {
    __shared__ int s[512];
    int tid = threadIdx.x;
    int v = (tid < n) ? bsum[tid] : 0;
    s[tid] = v;
    __syncthreads();
    for (int off = 1; off < 512; off <<= 1) {
        int t = (tid >= off) ? s[tid - off] : 0;
        __syncthreads();
        s[tid] += t;
        __syncthreads();
    }
    if (tid < n) boff[tid] = s[tid] - v;  // exclusive
}

__global__ void k_scan_final(const int* __restrict__ incl, const int* __restrict__ deg,
                             const int* __restrict__ boff, int* __restrict__ rs,
                             int* __restrict__ cursor, float* __restrict__ dis,
                             float* __restrict__ dinv) {
    int i = blockIdx.x * 256 + threadIdx.x;
    if (i < NN) {
        int d = deg[i];
        int v = incl[i] + boff[i >> 8];  // global inclusive
        int start = v - d;
        rs[i] = start;
        cursor[i] = start;
        if (i == NN - 1) rs[NN] = v;  // == EE
        float df = (float)(d + 1);
        dis[i] = rsqrtf(df);
        dinv[i] = 1.0f / df;
    }
}

// ---------------- CSR fill: (src, weight) pairs ----------------
__global__ void k_fill(const int* __restrict__ src, const int* __restrict__ dst,
                       const float* __restrict__ dis, int* __restrict__ cursor,
                       int2* __restrict__ ew) {
    int i = blockIdx.x * blockDim.x + threadIdx.x;
    int stride = gridDim.x * blockDim.x;
    for (; i < EE; i += stride) {
        int d = dst[i];
        int s = src[i];
        int pos = atomicAdd(&cursor[d], 1);
        ew[pos] = make_int2(s, __float_as_int(dis[s] * dis[d]));
    }
}

// ---------------- bf16 MFMA GEMM body: C[M][128] = A[M][K] @ W[K][128] ----------------
template <int K, bool AFP32>
__device__ __forceinline__ void gemm_body(const void* __restrict__ Ap,
                                          const ushort* __restrict__ Wt,
                                          ushort* __restrict__ C, int M, int blk) {
    __shared__ ushort As[64][40];   // [m][k], padded
    __shared__ ushort Ws[128][40];  // [n][k]
    int tid = threadIdx.x;
    int row0 = blk * 64;
    int wid = tid >> 6, lane = tid & 63;
    int wm = (wid & 1) * 32, wn = (wid >> 1) * 64;
    int lm = lane & 15, lk8 = (lane >> 4) * 8;

    f32x4 acc[4][2];
#pragma unroll
    for (int q = 0; q < 4; q++)
#pragma unroll
        for (int r = 0; r < 2; r++) acc[q][r] = (f32x4){0.f, 0.f, 0.f, 0.f};

    int arow = tid >> 2, akg = tid & 3;
    int gr = row0 + arow;

    for (int k0 = 0; k0 < K; k0 += 32) {
        if (AFP32) {
            const float* A = (const float*)Ap;
            float4 v0 = make_float4(0.f, 0.f, 0.f, 0.f), v1 = v0;
            if (gr < M) {
                const float* p = A + (size_t)gr * K + k0 + akg * 8;
                v0 = *(const float4*)(p);
                v1 = *(const float4*)(p + 4);
            }
            uint4 pk;
            pk.x = (uint)f2bf(v0.x) | ((uint)f2bf(v0.y) << 16);
            pk.y = (uint)f2bf(v0.z) | ((uint)f2bf(v0.w) << 16);
            pk.z = (uint)f2bf(v1.x) | ((uint)f2bf(v1.y) << 16);
            pk.w = (uint)f2bf(v1.z) | ((uint)f2bf(v1.w) << 16);
            *(uint4*)&As[arow][akg * 8] = pk;
        } else {
            const ushort* A = (const ushort*)Ap;
            uint4 v = make_uint4(0, 0, 0, 0);
            if (gr < M) v = *(const uint4*)(A + (size_t)gr * K + k0 + akg * 8);
            *(uint4*)&As[arow][akg * 8] = v;
        }
#pragma unroll
        for (int p = 0; p < 2; p++) {
            int idx = p * 256 + tid;
            int n = idx >> 2, kg = idx & 3;
            uint4 v = *(const uint4*)(Wt + (size_t)n * K + k0 + kg * 8);
            *(uint4*)&Ws[n][kg * 8] = v;
        }
        __syncthreads();

        bf16x8 xf[2], wf[4];
#pragma unroll
        for (int r = 0; r < 2; r++) xf[r] = *(const bf16x8*)&As[wm + r * 16 + lm][lk8];
#pragma unroll
        for (int q = 0; q < 4; q++) wf[q] = *(const bf16x8*)&Ws[wn + q * 16 + lm][lk8];
#pragma unroll
        for (int q = 0; q < 4; q++)
#pragma unroll
            for (int r = 0; r < 2; r++)
                acc[q][r] = __builtin_amdgcn_mfma_f32_16x16x32_bf16(wf[q], xf[r], acc[q][r], 0, 0, 0);
        __syncthreads();
    }

    int cn4 = (lane >> 4) * 4;
#pragma unroll
    for (int r = 0; r < 2; r++) {
        int m = row0 + wm + r * 16 + lm;
        if (m < M) {
#pragma unroll
            for (int q = 0; q < 4; q++) {
                int n = wn + q * 16 + cn4;
                uint2 o;
                o.x = (uint)f2bf(acc[q][r][0]) | ((uint)f2bf(acc[q][r][1]) << 16);
                o.y = (uint)f2bf(acc[q][r][2]) | ((uint)f2bf(acc[q][r][3]) << 16);
                *(uint2*)(C + (size_t)m * 128 + n) = o;
            }
        }
    }
}

// mega kernel 1: blocks [0,DEG_BLKS) count degrees; rest do GEMM1
__global__ __launch_bounds__(256) void k_mega1(const float* __restrict__ x,
                                               const ushort* __restrict__ Wt1,
                                               ushort* __restrict__ C,
                                               const int* __restrict__ dst,
                                               int* __restrict__ deg) {
    if (blockIdx.x < DEG_BLKS) {
        int i = blockIdx.x * 256 + threadIdx.x;
        int stride = DEG_BLKS * 256;
        for (; i < EE; i += stride) atomicAdd(&deg[dst[i]], 1);
    } else {
        gemm_body<IND, true>(x, Wt1, C, NN, blockIdx.x - DEG_BLKS);
    }
}

__global__ __launch_bounds__(256) void k_gemm2(const ushort* __restrict__ A,
                                               const ushort* __restrict__ Wt,
                                               ushort* __restrict__ C) {
    gemm_body<HIDD, false>(A, Wt, C, NN, blockIdx.x);
}

// ---------------- aggregation over bf16 h (scalarized edges, 16-deep) ----------------
// HEAD=true additionally computes out[node][16] = emb_row @ Wl + bl.
template <bool HEAD>
__global__ __launch_bounds__(256) void k_agg_bf(const ushort* __restrict__ h,
                                                const int* __restrict__ rs,
                                                const int2* __restrict__ ew,
                                                const float* __restrict__ dinv,
                                                const float* __restrict__ bias,
                                                void* __restrict__ yv,
                                                const float* __restrict__ Wl,
                                                const float* __restrict__ bl,
                                                float* __restrict__ outp) {
    __shared__ float wl_s[HEAD ? 128 * 17 : 1];
    int tid = threadIdx.x;
    int lane = tid & 63;
    if (HEAD) {
        for (int i = tid; i < 2048; i += 256) wl_s[(i >> 4) * 17 + (i & 15)] = Wl[i];
        __syncthreads();
    }
    const uint* h32 = (const uint*)h;
    float b0 = bias[lane * 2], b1 = bias[lane * 2 + 1];

    for (int node = blockIdx.x * 4 + (tid >> 6); node < NN; node += gridDim.x * 4) {
        float dv = dinv[node];
        uint sv = h32[(size_t)node * 64 + lane];
        float acc0 = __uint_as_float(sv << 16) * dv;
        float acc1 = __uint_as_float(sv & 0xffff0000u) * dv;
        int e  = __builtin_amdgcn_readfirstlane(rs[node]);
        int e1 = __builtin_amdgcn_readfirstlane(rs[node + 1]);

#define EL(i) int2 p##i = ew[e + i]; uint g##i = h32[(size_t)(uint)p##i.x * 64 + lane];
#define EA(i) { float w##i = __int_as_float(p##i.y); \
    acc0 += w##i * __uint_as_float(g##i << 16); \
    acc1 += w##i * __uint_as_float(g##i & 0xffff0000u); }

        for (; e + 16 <= e1; e += 16) {
            EL(0) EL(1) EL(2) EL(3) EL(4) EL(5) EL(6) EL(7)
            EL(8) EL(9) EL(10) EL(11) EL(12) EL(13) EL(14) EL(15)
            EA(0) EA(1) EA(2) EA(3) EA(4) EA(5) EA(6) EA(7)
            EA(8) EA(9) EA(10) EA(11) EA(12) EA(13) EA(14) EA(15)
        }
        for (; e + 4 <= e1; e += 4) {
            EL(0) EL(1) EL(2) EL(3)
            EA(0) EA(1) EA(2) EA(3)
        }
        for (; e < e1; ++e) {
            EL(0)
            EA(0)
        }
#undef EL
#undef EA

        acc0 = fmaxf(acc0 + b0, 0.0f);
        acc1 = fmaxf(acc1 + b1, 0.0f);

        if (!HEAD) {
            ((uint*)yv)[(size_t)node * 64 + lane] =
                (uint)f2bf(acc0) | ((uint)f2bf(acc1) << 16);
        } else {
            ((float2*)yv)[(size_t)node * 64 + lane] = make_float2(acc0, acc1);
            // head: out[o] = sum_k emb[k]*Wl[k][o] + bl[o]; lane holds k=2l,2l+1
            float part[16];
#pragma unroll
            for (int o = 0; o < 16; o++)
                part[o] = acc0 * wl_s[(lane * 2) * 17 + o] + acc1 * wl_s[(lane * 2 + 1) * 17 + o];
#pragma unroll
            for (int s = 1; s < 64; s <<= 1) {
#pragma unroll
                for (int o = 0; o < 16; o++) part[o] += __shfl_xor(part[o], s, 64);
            }
            if (lane == 0) {
                float* op = outp + (size_t)node * 16;
                *(float4*)(op + 0)  = make_float4(part[0] + bl[0], part[1] + bl[1], part[2] + bl[2], part[3] + bl[3]);
                *(float4*)(op + 4)  = make_float4(part[4] + bl[4], part[5] + bl[5], part[6] + bl[6], part[7] + bl[7]);
                *(float4*)(op + 8)  = make_float4(part[8] + bl[8], part[9] + bl[9], part[10] + bl[10], part[11] + bl[11]);
                *(float4*)(op + 12) = make_float4(part[12] + bl[12], part[13] + bl[13], part[14] + bl[14], part[15] + bl[15]);
            }
        }
    }
}

extern "C" void kernel_launch(void* const* d_in, const int* in_sizes, int n_in,
                              void* d_out, int out_size, void* d_ws, size_t ws_size,
                              hipStream_t stream) {
    const float* x  = (const float*)d_in[0];
    const int* ei   = (const int*)d_in[1];  // [2][E]: row0=src, row1=dst
    const float* W1 = (const float*)d_in[2];
    const float* b1 = (const float*)d_in[3];
    const float* W2 = (const float*)d_in[4];
    const float* b2 = (const float*)d_in[5];
    const float* Wl = (const float*)d_in[6];
    const float* bl = (const float*)d_in[7];
    const int* src = ei;
    const int* dst = ei + EE;

    float* outp = (float*)d_out;             // [N][16]
    float* emb  = outp + (size_t)NN * OUTD;  // [N][128] fp32

    int2* ew    = (int2*)d_ws;                        // E pairs (src, w)
    ushort* h_a = (ushort*)(ew + EE);                 // N*128 bf16
    ushort* h_b = h_a + (size_t)NN * 128;             // N*128 bf16
    ushort* Wt1 = h_b + (size_t)NN * 128;             // 128*512 bf16
    ushort* Wt2 = Wt1 + 128 * 512;                    // 128*128 bf16
    int* deg    = (int*)(Wt2 + 128 * 128);
    float* dis  = (float*)(deg + NN);
    float* dinv = dis + NN;
    int* incl   = (int*)(dinv + NN);
    int* rs     = incl + NN;                          // N+1
    int* cursor = rs + NN + 8;
    int* bsum   = cursor + NN;
    int* boff   = bsum + 512;

    const int NB_N = (NN + 255) / 256;  // 391

    hipMemsetAsync(deg, 0, (size_t)NN * sizeof(int), stream);
    k_prep<<<320, 256, 0, stream>>>(W1, W2, Wt1, Wt2);
    // gemm1 (x@W1 -> h_a bf16)  ||  degree count
    k_mega1<<<DEG_BLKS + GEMM_BLKS, 256, 0, stream>>>(x, Wt1, h_a, dst, deg);
    k_scan_local<<<NB_N, 256, 0, stream>>>(deg, incl, bsum);
    k_scan_bsum<<<1, 512, 0, stream>>>(bsum, boff, NB_N);
    k_scan_final<<<NB_N, 256, 0, stream>>>(incl, deg, boff, rs, cursor, dis, dinv);
    k_fill<<<2048, 256, 0, stream>>>(src, dst, dis, cursor, ew);

    // layer 1 agg: h_b = bf16(relu(agg(h_a) + b1))
    k_agg_bf<false><<<2048, 256, 0, stream>>>(h_a, rs, ew, dinv, b1, h_b,
                                              nullptr, nullptr, nullptr);
    // layer 2: h_a = bf16(h_b @ W2); emb = fp32(relu(agg(h_a) + b2)); out = emb@Wl+bl
    k_gemm2<<<GEMM_BLKS, 256, 0, stream>>>(h_b, Wt2, h_a);
    k_agg_bf<true><<<2048, 256, 0, stream>>>(h_a, rs, ew, dinv, b2, emb,
                                             Wl, bl, outp);
}

// Round 5
// 383.025 us; speedup vs baseline: 2.1739x; 1.0235x over previous
//
#include <hip/hip_runtime.h>

#define NN 100000
#define EE 1600000
#define IND 512
#define HIDD 128
#define OUTD 16
#define DEG_BLKS 128
#define GEMM_BLKS 1563  // ceil(NN/64)

typedef __bf16 bf16x8 __attribute__((ext_vector_type(8)));
typedef float f32x4 __attribute__((ext_vector_type(4)));

__device__ __forceinline__ ushort f2bf(float f) {
    union { float f; uint u; } v; v.f = f;
    uint r = v.u + 0x7FFFu + ((v.u >> 16) & 1u);
    return (ushort)(r >> 16);
}

// ---------------- W prep: both layers in one launch ----------------
__global__ void k_prep(const float* __restrict__ W1, const float* __restrict__ W2,
                       ushort* __restrict__ Wt1, ushort* __restrict__ Wt2) {
    int b = blockIdx.x, tid = threadIdx.x;
    if (b < 256) {  // W1: 512x128 -> Wt1[128][512]
        int i = b * 256 + tid;
        int k = i >> 7, n = i & 127;
        Wt1[n * 512 + k] = f2bf(W1[i]);
    } else {        // W2: 128x128 -> Wt2[128][128]
        int i = (b - 256) * 256 + tid;
        int k = i >> 7, n = i & 127;
        Wt2[n * 128 + k] = f2bf(W2[i]);
    }
}

// ---------------- scan (3 phases; norm fused into final) ----------------
__global__ void k_scan_local(const int* __restrict__ deg, int* __restrict__ incl,
                             int* __restrict__ bsum) {
    __shared__ int s[256];
    int tid = threadIdx.x;
    int i = blockIdx.x * 256 + tid;
    int v = (i < NN) ? deg[i] : 0;
    s[tid] = v;
    __syncthreads();
    for (int off = 1; off < 256; off <<= 1) {
        int t = (tid >= off) ? s[tid - off] : 0;
        __syncthreads();
        s[tid] += t;
        __syncthreads();
    }
    if (i < NN) incl[i] = s[tid];
    if (tid == 255) bsum[blockIdx.x] = s[255];
}

__global__ void k_scan_bsum(const int* __restrict__ bsum, int* __restrict__ boff, int n) {
    __shared__ int s[512];
    int tid = threadIdx.x;
    int v = (tid < n) ? bsum[tid] : 0;
    s[tid] = v;
    __syncthreads();
    for (int off = 1; off < 512; off <<= 1) {
        int t = (tid >= off) ? s[tid - off] : 0;
        __syncthreads();
        s[tid] += t;
        __syncthreads();
    }
    if (tid < n) boff[tid] = s[tid] - v;  // exclusive
}

__global__ void k_scan_final(const int* __restrict__ incl, const int* __restrict__ deg,
                             const int* __restrict__ boff, int* __restrict__ rs,
                             int* __restrict__ cursor, float* __restrict__ dis,
                             float* __restrict__ dinv) {
    int i = blockIdx.x * 256 + threadIdx.x;
    if (i < NN) {
        int d = deg[i];
        int v = incl[i] + boff[i >> 8];  // global inclusive
        int start = v - d;
        rs[i] = start;
        cursor[i] = start;
        if (i == NN - 1) rs[NN] = v;  // == EE
        float df = (float)(d + 1);
        dis[i] = rsqrtf(df);
        dinv[i] = 1.0f / df;
    }
}

// ---------------- CSR fill: (src, weight) pairs ----------------
__global__ void k_fill(const int* __restrict__ src, const int* __restrict__ dst,
                       const float* __restrict__ dis, int* __restrict__ cursor,
                       int2* __restrict__ ew) {
    int i = blockIdx.x * blockDim.x + threadIdx.x;
    int stride = gridDim.x * blockDim.x;
    for (; i < EE; i += stride) {
        int d = dst[i];
        int s = src[i];
        int pos = atomicAdd(&cursor[d], 1);
        ew[pos] = make_int2(s, __float_as_int(dis[s] * dis[d]));
    }
}

// ---------------- bf16 MFMA GEMM body: C[M][128] = A[M][K] @ W[K][128] ----------------
template <int K, bool AFP32>
__device__ __forceinline__ void gemm_body(const void* __restrict__ Ap,
                                          const ushort* __restrict__ Wt,
                                          ushort* __restrict__ C, int M, int blk) {
    __shared__ ushort As[64][40];   // [m][k], padded
    __shared__ ushort Ws[128][40];  // [n][k]
    int tid = threadIdx.x;
    int row0 = blk * 64;
    int wid = tid >> 6, lane = tid & 63;
    int wm = (wid & 1) * 32, wn = (wid >> 1) * 64;
    int lm = lane & 15, lk8 = (lane >> 4) * 8;

    f32x4 acc[4][2];
#pragma unroll
    for (int q = 0; q < 4; q++)
#pragma unroll
        for (int r = 0; r < 2; r++) acc[q][r] = (f32x4){0.f, 0.f, 0.f, 0.f};

    int arow = tid >> 2, akg = tid & 3;
    int gr = row0 + arow;

    for (int k0 = 0; k0 < K; k0 += 32) {
        if (AFP32) {
            const float* A = (const float*)Ap;
            float4 v0 = make_float4(0.f, 0.f, 0.f, 0.f), v1 = v0;
            if (gr < M) {
                const float* p = A + (size_t)gr * K + k0 + akg * 8;
                v0 = *(const float4*)(p);
                v1 = *(const float4*)(p + 4);
            }
            uint4 pk;
            pk.x = (uint)f2bf(v0.x) | ((uint)f2bf(v0.y) << 16);
            pk.y = (uint)f2bf(v0.z) | ((uint)f2bf(v0.w) << 16);
            pk.z = (uint)f2bf(v1.x) | ((uint)f2bf(v1.y) << 16);
            pk.w = (uint)f2bf(v1.z) | ((uint)f2bf(v1.w) << 16);
            *(uint4*)&As[arow][akg * 8] = pk;
        } else {
            const ushort* A = (const ushort*)Ap;
            uint4 v = make_uint4(0, 0, 0, 0);
            if (gr < M) v = *(const uint4*)(A + (size_t)gr * K + k0 + akg * 8);
            *(uint4*)&As[arow][akg * 8] = v;
        }
#pragma unroll
        for (int p = 0; p < 2; p++) {
            int idx = p * 256 + tid;
            int n = idx >> 2, kg = idx & 3;
            uint4 v = *(const uint4*)(Wt + (size_t)n * K + k0 + kg * 8);
            *(uint4*)&Ws[n][kg * 8] = v;
        }
        __syncthreads();

        bf16x8 xf[2], wf[4];
#pragma unroll
        for (int r = 0; r < 2; r++) xf[r] = *(const bf16x8*)&As[wm + r * 16 + lm][lk8];
#pragma unroll
        for (int q = 0; q < 4; q++) wf[q] = *(const bf16x8*)&Ws[wn + q * 16 + lm][lk8];
#pragma unroll
        for (int q = 0; q < 4; q++)
#pragma unroll
            for (int r = 0; r < 2; r++)
                acc[q][r] = __builtin_amdgcn_mfma_f32_16x16x32_bf16(wf[q], xf[r], acc[q][r], 0, 0, 0);
        __syncthreads();
    }

    int cn4 = (lane >> 4) * 4;
#pragma unroll
    for (int r = 0; r < 2; r++) {
        int m = row0 + wm + r * 16 + lm;
        if (m < M) {
#pragma unroll
            for (int q = 0; q < 4; q++) {
                int n = wn + q * 16 + cn4;
                uint2 o;
                o.x = (uint)f2bf(acc[q][r][0]) | ((uint)f2bf(acc[q][r][1]) << 16);
                o.y = (uint)f2bf(acc[q][r][2]) | ((uint)f2bf(acc[q][r][3]) << 16);
                *(uint2*)(C + (size_t)m * 128 + n) = o;
            }
        }
    }
}

// mega kernel 1: blocks [0,DEG_BLKS) count degrees; rest do GEMM1
__global__ __launch_bounds__(256) void k_mega1(const float* __restrict__ x,
                                               const ushort* __restrict__ Wt1,
                                               ushort* __restrict__ C,
                                               const int* __restrict__ dst,
                                               int* __restrict__ deg) {
    if (blockIdx.x < DEG_BLKS) {
        int i = blockIdx.x * 256 + threadIdx.x;
        int stride = DEG_BLKS * 256;
        for (; i < EE; i += stride) atomicAdd(&deg[dst[i]], 1);
    } else {
        gemm_body<IND, true>(x, Wt1, C, NN, blockIdx.x - DEG_BLKS);
    }
}

__global__ __launch_bounds__(256) void k_gemm2(const ushort* __restrict__ A,
                                               const ushort* __restrict__ Wt,
                                               ushort* __restrict__ C) {
    gemm_body<HIDD, false>(A, Wt, C, NN, blockIdx.x);
}

// ---------------- aggregation over bf16 h ----------------
// One node per wave. Half-wave edge pairing: lanes 0-31 process even edges,
// lanes 32-63 odd edges; each lane loads uint2 (4 dims), 32 lanes cover the
// 128-dim row. 8-pair main loop = 16 edges in flight per wave.
template <bool OUTF32>
__global__ __launch_bounds__(256) void k_agg(const ushort* __restrict__ h,
                                             const int* __restrict__ rs,
                                             const int2* __restrict__ ew,
                                             const float* __restrict__ dinv,
                                             const float* __restrict__ bias,
                                             void* __restrict__ yv) {
    int node = blockIdx.x * 4 + (threadIdx.x >> 6);
    int lane = threadIdx.x & 63;
    if (node >= NN) return;
    int half = lane >> 5, c = lane & 31;
    const uint2* h64 = (const uint2*)h;

    float acc0 = 0.f, acc1 = 0.f, acc2 = 0.f, acc3 = 0.f;
    if (half == 0) {  // self-loop term, lower half only
        float dv = dinv[node];
        uint2 sv = h64[(size_t)node * 32 + c];
        acc0 = __uint_as_float(sv.x << 16) * dv;
        acc1 = __uint_as_float(sv.x & 0xffff0000u) * dv;
        acc2 = __uint_as_float(sv.y << 16) * dv;
        acc3 = __uint_as_float(sv.y & 0xffff0000u) * dv;
    }

    int e = rs[node], e1 = rs[node + 1];

#define EL(i) int2 p##i = ew[e + 2 * i + half]; \
              uint2 g##i = h64[(size_t)(uint)p##i.x * 32 + c];
#define EA(i) { float w##i = __int_as_float(p##i.y); \
    acc0 += w##i * __uint_as_float(g##i.x << 16); \
    acc1 += w##i * __uint_as_float(g##i.x & 0xffff0000u); \
    acc2 += w##i * __uint_as_float(g##i.y << 16); \
    acc3 += w##i * __uint_as_float(g##i.y & 0xffff0000u); }

    for (; e + 16 <= e1; e += 16) {  // 8 pairs = 16 edges in flight
        EL(0) EL(1) EL(2) EL(3) EL(4) EL(5) EL(6) EL(7)
        EA(0) EA(1) EA(2) EA(3) EA(4) EA(5) EA(6) EA(7)
    }
    for (; e + 4 <= e1; e += 4) {    // 2 pairs = 4 edges
        EL(0) EL(1)
        EA(0) EA(1)
    }
    if (e + 2 <= e1) {               // 1 pair
        EL(0)
        EA(0)
        e += 2;
    }
    if (e < e1 && half == 0) {       // final odd edge, lower half only
        int2 p = ew[e];
        uint2 g = h64[(size_t)(uint)p.x * 32 + c];
        float w = __int_as_float(p.y);
        acc0 += w * __uint_as_float(g.x << 16);
        acc1 += w * __uint_as_float(g.x & 0xffff0000u);
        acc2 += w * __uint_as_float(g.y << 16);
        acc3 += w * __uint_as_float(g.y & 0xffff0000u);
    }
#undef EL
#undef EA

    // merge halves
    acc0 += __shfl_xor(acc0, 32, 64);
    acc1 += __shfl_xor(acc1, 32, 64);
    acc2 += __shfl_xor(acc2, 32, 64);
    acc3 += __shfl_xor(acc3, 32, 64);

    if (half == 0) {
        float4 bv = *(const float4*)(bias + c * 4);
        acc0 = fmaxf(acc0 + bv.x, 0.f);
        acc1 = fmaxf(acc1 + bv.y, 0.f);
        acc2 = fmaxf(acc2 + bv.z, 0.f);
        acc3 = fmaxf(acc3 + bv.w, 0.f);
        if (OUTF32) {
            *(float4*)((float*)yv + (size_t)node * 128 + c * 4) =
                make_float4(acc0, acc1, acc2, acc3);
        } else {
            uint2 o;
            o.x = (uint)f2bf(acc0) | ((uint)f2bf(acc1) << 16);
            o.y = (uint)f2bf(acc2) | ((uint)f2bf(acc3) << 16);
            *(uint2*)((ushort*)yv + (size_t)node * 128 + c * 4) = o;
        }
    }
}

// ---------------- head: out[N][16] = emb[N][128] @ Wl[128][16] + bl ----------------
__global__ __launch_bounds__(256) void k_out(const float* __restrict__ emb,
                                             const float* __restrict__ Wl,
                                             const float* __restrict__ bl,
                                             float* __restrict__ out) {
    __shared__ float wl_s[128 * 16];
    __shared__ float es[16][129];
    int tid = threadIdx.x;
    int row0 = blockIdx.x * 16;
#pragma unroll
    for (int p = 0; p < 8; p++) wl_s[p * 256 + tid] = Wl[p * 256 + tid];
#pragma unroll
    for (int p = 0; p < 8; p++) {
        int idx = p * 256 + tid;
        int r = idx >> 7, c = idx & 127;
        int gr = row0 + r;
        es[r][c] = (gr < NN) ? emb[(size_t)gr * 128 + c] : 0.0f;
    }
    __syncthreads();
    int r = tid >> 4, o = tid & 15;
    float acc = bl[o];
#pragma unroll
    for (int k = 0; k < 128; k++) acc += es[r][k] * wl_s[k * 16 + o];
    int gr = row0 + r;
    if (gr < NN) out[(size_t)gr * 16 + o] = acc;
}

extern "C" void kernel_launch(void* const* d_in, const int* in_sizes, int n_in,
                              void* d_out, int out_size, void* d_ws, size_t ws_size,
                              hipStream_t stream) {
    const float* x  = (const float*)d_in[0];
    const int* ei   = (const int*)d_in[1];  // [2][E]: row0=src, row1=dst
    const float* W1 = (const float*)d_in[2];
    const float* b1 = (const float*)d_in[3];
    const float* W2 = (const float*)d_in[4];
    const float* b2 = (const float*)d_in[5];
    const float* Wl = (const float*)d_in[6];
    const float* bl = (const float*)d_in[7];
    const int* src = ei;
    const int* dst = ei + EE;

    float* outp = (float*)d_out;             // [N][16]
    float* emb  = outp + (size_t)NN * OUTD;  // [N][128] fp32

    int2* ew    = (int2*)d_ws;                        // E pairs (src, w)
    ushort* h_a = (ushort*)(ew + EE);                 // N*128 bf16
    ushort* h_b = h_a + (size_t)NN * 128;             // N*128 bf16
    ushort* Wt1 = h_b + (size_t)NN * 128;             // 128*512 bf16
    ushort* Wt2 = Wt1 + 128 * 512;                    // 128*128 bf16
    int* deg    = (int*)(Wt2 + 128 * 128);
    float* dis  = (float*)(deg + NN);
    float* dinv = dis + NN;
    int* incl   = (int*)(dinv + NN);
    int* rs     = incl + NN;                          // N+1
    int* cursor = rs + NN + 8;
    int* bsum   = cursor + NN;
    int* boff   = bsum + 512;

    const int NB_N = (NN + 255) / 256;  // 391

    hipMemsetAsync(deg, 0, (size_t)NN * sizeof(int), stream);
    k_prep<<<320, 256, 0, stream>>>(W1, W2, Wt1, Wt2);
    // gemm1 (x@W1 -> h_a bf16)  ||  degree count
    k_mega1<<<DEG_BLKS + GEMM_BLKS, 256, 0, stream>>>(x, Wt1, h_a, dst, deg);
    k_scan_local<<<NB_N, 256, 0, stream>>>(deg, incl, bsum);
    k_scan_bsum<<<1, 512, 0, stream>>>(bsum, boff, NB_N);
    k_scan_final<<<NB_N, 256, 0, stream>>>(incl, deg, boff, rs, cursor, dis, dinv);
    k_fill<<<2048, 256, 0, stream>>>(src, dst, dis, cursor, ew);

    // layer 1 agg: h_b = bf16(relu(agg(h_a) + b1))
    k_agg<false><<<(NN + 3) / 4, 256, 0, stream>>>(h_a, rs, ew, dinv, b1, h_b);
    // layer 2: h_a = bf16(h_b @ W2); emb = fp32(relu(agg(h_a) + b2))
    k_gemm2<<<GEMM_BLKS, 256, 0, stream>>>(h_b, Wt2, h_a);
    k_agg<true><<<(NN + 3) / 4, 256, 0, stream>>>(h_a, rs, ew, dinv, b2, emb);
    // head
    k_out<<<(NN + 15) / 16, 256, 0, stream>>>(emb, Wl, bl, outp);
}